// Round 1
// baseline (415.671 us; speedup 1.0000x reference)
//
#include <hip/hip_runtime.h>
#include <stdint.h>

#define N_G   1024
#define H_IMG 128
#define W_IMG 128
#define FXc   128.0f
#define FYc   128.0f

// ---------------- Kernel 1: preprocess + bitonic sort + gather ----------------
// One block, 1024 threads (thread n owns gaussian n).
__global__ __launch_bounds__(1024) void prep_sort_kernel(
    const float* __restrict__ means3D,   // (N,3)
    const float* __restrict__ opac,      // (N,1)
    const float* __restrict__ shs,       // (N,16,3)
    const float* __restrict__ scales,    // (N,3)
    const float* __restrict__ rot,       // (N,4)
    const float* __restrict__ vm,        // (4,4)
    const float* __restrict__ pm,        // (4,4)
    const float* __restrict__ campos,    // (3,)
    float*       __restrict__ radii_out, // d_out + 3*H*W (written as float ints)
    float*       __restrict__ payload,   // ws: N*12 floats
    float*       __restrict__ sorted_payload, // ws: N*12 floats
    int*         __restrict__ count_out)
{
    __shared__ unsigned long long keys[N_G];
    __shared__ int cnt;
    const int n = threadIdx.x;

    // ---------- preprocess gaussian n ----------
    {
        float mx = means3D[n*3+0], my = means3D[n*3+1], mz = means3D[n*3+2];

        // p_view = [m,1] @ V  (row-vector convention)
        float pv0   = mx*vm[0] + my*vm[4] + mz*vm[8]  + vm[12];
        float pv1   = mx*vm[1] + my*vm[5] + mz*vm[9]  + vm[13];
        float depth = mx*vm[2] + my*vm[6] + mz*vm[10] + vm[14];
        bool dvalid = depth > 0.2f;

        // p_hom = [m,1] @ P ; p_proj = p_hom/(w+1e-7)
        float ph0 = mx*pm[0] + my*pm[4] + mz*pm[8]  + pm[12];
        float ph1 = mx*pm[1] + my*pm[5] + mz*pm[9]  + pm[13];
        float ph3 = mx*pm[3] + my*pm[7] + mz*pm[11] + pm[15];
        float invw = 1.0f / (ph3 + 1e-7f);
        float pp0 = ph0 * invw, pp1 = ph1 * invw;

        // quaternion -> R
        float q0 = rot[n*4+0], q1 = rot[n*4+1], q2 = rot[n*4+2], q3 = rot[n*4+3];
        float qn = sqrtf(q0*q0 + q1*q1 + q2*q2 + q3*q3);
        float qr = q0/qn, qx = q1/qn, qy = q2/qn, qz = q3/qn;
        float R00 = 1.f - 2.f*(qy*qy + qz*qz), R01 = 2.f*(qx*qy - qr*qz), R02 = 2.f*(qx*qz + qr*qy);
        float R10 = 2.f*(qx*qy + qr*qz), R11 = 1.f - 2.f*(qx*qx + qz*qz), R12 = 2.f*(qy*qz - qr*qx);
        float R20 = 2.f*(qx*qz - qr*qy), R21 = 2.f*(qy*qz + qr*qx), R22 = 1.f - 2.f*(qx*qx + qy*qy);

        float s0 = scales[n*3+0], s1 = scales[n*3+1], s2 = scales[n*3+2];
        float M00=R00*s0, M01=R01*s1, M02=R02*s2;
        float M10=R10*s0, M11=R11*s1, M12=R12*s2;
        float M20=R20*s0, M21=R21*s1, M22=R22*s2;

        // Sigma = M M^T (symmetric)
        float S00 = M00*M00 + M01*M01 + M02*M02;
        float S01 = M00*M10 + M01*M11 + M02*M12;
        float S02 = M00*M20 + M01*M21 + M02*M22;
        float S11 = M10*M10 + M11*M11 + M12*M12;
        float S12 = M10*M20 + M11*M21 + M12*M22;
        float S22 = M20*M20 + M21*M21 + M22*M22;

        // Jacobian (uses dvalid = depth>0.2 only, like reference)
        float tz   = dvalid ? depth : 1.0f;
        float txtz = fminf(fmaxf(pv0 / tz, -0.65f), 0.65f) * tz;
        float tytz = fminf(fmaxf(pv1 / tz, -0.65f), 0.65f) * tz;
        float J00 = FXc / tz, J02 = -FXc * txtz / (tz*tz);
        float J11 = FYc / tz, J12 = -FYc * tytz / (tz*tz);

        // T2 = J @ W^T  where Wr[j][k] = V[k][j]
        float T20k0 = J00*vm[0] + J02*vm[2];
        float T20k1 = J00*vm[4] + J02*vm[6];
        float T20k2 = J00*vm[8] + J02*vm[10];
        float T21k0 = J11*vm[1] + J12*vm[2];
        float T21k1 = J11*vm[5] + J12*vm[6];
        float T21k2 = J11*vm[9] + J12*vm[10];

        // cov2 = T2 Sigma T2^T
        float U00 = T20k0*S00 + T20k1*S01 + T20k2*S02;
        float U01 = T20k0*S01 + T20k1*S11 + T20k2*S12;
        float U02 = T20k0*S02 + T20k1*S12 + T20k2*S22;
        float U10 = T21k0*S00 + T21k1*S01 + T21k2*S02;
        float U11 = T21k0*S01 + T21k1*S11 + T21k2*S12;
        float U12 = T21k0*S02 + T21k1*S12 + T21k2*S22;
        float cov00 = U00*T20k0 + U01*T20k1 + U02*T20k2;
        float cov01 = U00*T21k0 + U01*T21k1 + U02*T21k2;
        float cov11 = U10*T21k0 + U11*T21k1 + U12*T21k2;

        float a = cov00 + 0.3f, b = cov01, c = cov11 + 0.3f;
        float det = a*c - b*b;
        bool valid = dvalid && (det > 0.0f);
        float inv_det = (det > 0.0f) ? (1.0f / det) : 1.0f;
        float conA = c * inv_det, conB = -b * inv_det, conC = a * inv_det;

        float mid  = 0.5f * (a + c);
        float lam1 = mid + sqrtf(fmaxf(0.1f, mid*mid - det));
        float radf = valid ? ceilf(3.0f * sqrtf(lam1)) : 0.0f;
        radii_out[n] = radf;  // int-valued, stored in the f32 output buffer

        float gx = ((pp0 + 1.0f) * (float)W_IMG - 1.0f) * 0.5f;
        float gy = ((pp1 + 1.0f) * (float)H_IMG - 1.0f) * 0.5f;

        // SH -> RGB
        float dx = mx - campos[0], dy = my - campos[1], dz = mz - campos[2];
        float dn = sqrtf(dx*dx + dy*dy + dz*dz);
        float sx = dx/dn, sy = dy/dn, sz = dz/dn;
        float xx = sx*sx, yy = sy*sy, zz = sz*sz;
        float xy = sx*sy, yz = sy*sz, xz = sx*sz;
        const float* sh = shs + n*48;
        float col[3];
        #pragma unroll
        for (int ch = 0; ch < 3; ++ch) {
            float res = 0.28209479177387814f * sh[0*3+ch]
                - 0.4886025119029199f * sy * sh[1*3+ch]
                + 0.4886025119029199f * sz * sh[2*3+ch]
                - 0.4886025119029199f * sx * sh[3*3+ch]
                + 1.0925484305920792f  * xy * sh[4*3+ch]
                + (-1.0925484305920792f) * yz * sh[5*3+ch]
                + 0.31539156525252005f * (2.f*zz - xx - yy) * sh[6*3+ch]
                + (-1.0925484305920792f) * xz * sh[7*3+ch]
                + 0.5462742152960396f  * (xx - yy) * sh[8*3+ch]
                + (-0.5900435899266435f) * sy * (3.f*xx - yy) * sh[9*3+ch]
                + 2.890611442640554f   * xy * sz * sh[10*3+ch]
                + (-0.4570457994644658f) * sy * (4.f*zz - xx - yy) * sh[11*3+ch]
                + 0.3731763325901154f  * sz * (2.f*zz - 3.f*xx - 3.f*yy) * sh[12*3+ch]
                + (-0.4570457994644658f) * sx * (4.f*zz - xx - yy) * sh[13*3+ch]
                + 1.445305721320277f   * sz * (xx - yy) * sh[14*3+ch]
                + (-0.5900435899266435f) * sx * (xx - 3.f*yy) * sh[15*3+ch];
            col[ch] = fmaxf(res + 0.5f, 0.0f);
        }

        float op = opac[n];
        float* pl = payload + n*12;
        pl[0] = gx;   pl[1] = gy;   pl[2] = conA; pl[3] = conB;
        pl[4] = conC; pl[5] = op;   pl[6] = col[0]; pl[7] = col[1];
        pl[8] = col[2]; pl[9] = 0.f; pl[10] = 0.f; pl[11] = 0.f;

        // sort key: (depth_bits | +inf) << 32 | index  -> exact stable argsort
        unsigned int kb = valid ? __float_as_uint(depth) : 0x7F800000u;
        keys[n] = ((unsigned long long)kb << 32) | (unsigned int)n;
    }

    if (n == 0) cnt = 0;
    __syncthreads();  // keys visible + payload global writes visible to block

    // ---------- bitonic sort (ascending) ----------
    for (int k = 2; k <= N_G; k <<= 1) {
        for (int j = k >> 1; j > 0; j >>= 1) {
            int l = n ^ j;
            if (l > n) {
                bool asc = ((n & k) == 0);
                unsigned long long ka = keys[n], kb2 = keys[l];
                if ((ka > kb2) == asc) { keys[n] = kb2; keys[l] = ka; }
            }
            __syncthreads();
        }
    }

    // ---------- count valid + gather payload into sorted order ----------
    unsigned long long kk = keys[n];
    if ((kk >> 32) < 0x7F800000ull) atomicAdd(&cnt, 1);
    int src = (int)(kk & 0xFFFFFFFFu);
    float4* sp = (float4*)(sorted_payload + n*12);
    const float4* pp = (const float4*)(payload + src*12);
    sp[0] = pp[0]; sp[1] = pp[1]; sp[2] = pp[2];
    __syncthreads();
    if (n == 0) *count_out = cnt;
}

// ---------------- Kernel 2: per-pixel front-to-back blend ----------------
__global__ __launch_bounds__(64) void raster_kernel(
    const float* __restrict__ sorted_payload,
    const int*   __restrict__ count_ptr,
    const float* __restrict__ bg,
    float*       __restrict__ out)
{
    int p = blockIdx.x * 64 + threadIdx.x;   // 0..16383
    float px = (float)(p & (W_IMG - 1));
    float py = (float)(p >> 7);
    int count = *count_ptr;

    float T = 1.0f;     // cumprod(1 - raw alpha)   (gates the 1e-4 cutoff)
    float Tfin = 1.0f;  // prod(1 - ae)
    float cr = 0.f, cg = 0.f, cb = 0.f;

    for (int i = 0; i < count; ++i) {
        const float4* g4 = (const float4*)(sorted_payload + i*12);
        float4 g0 = g4[0];  // gx, gy, conA, conB
        float4 g1 = g4[1];  // conC, op, r, g
        float4 g2 = g4[2];  // b, pad...

        float dx = g0.x - px, dy = g0.y - py;
        float power = -0.5f * (g0.z*dx*dx + g1.x*dy*dy) - g0.w*dx*dy;
        if (power > 0.0f) continue;                       // alpha -> 0
        float alpha = fminf(0.99f, g1.y * expf(power));
        if (alpha < (1.0f/255.0f)) continue;              // alpha -> 0

        float Tnew = T * (1.0f - alpha);                  // Tinc_i
        if (Tnew < 1e-4f) break;   // ae_i and all later ae are 0: exact early-out

        float w = T * alpha;                              // Texc * ae
        cr += w * g1.z; cg += w * g1.w; cb += w * g2.x;
        Tfin *= (1.0f - alpha);
        T = Tnew;
    }

    out[p]                       = cr + bg[0] * Tfin;
    out[H_IMG*W_IMG + p]         = cg + bg[1] * Tfin;
    out[2*H_IMG*W_IMG + p]       = cb + bg[2] * Tfin;
}

extern "C" void kernel_launch(void* const* d_in, const int* in_sizes, int n_in,
                              void* d_out, int out_size, void* d_ws, size_t ws_size,
                              hipStream_t stream) {
    const float* means3D = (const float*)d_in[0];
    // d_in[1] = means2D (unused)
    const float* opac    = (const float*)d_in[2];
    const float* shs     = (const float*)d_in[3];
    const float* scales  = (const float*)d_in[4];
    const float* rot     = (const float*)d_in[5];
    const float* vm      = (const float*)d_in[6];
    const float* pm      = (const float*)d_in[7];
    const float* campos  = (const float*)d_in[8];
    const float* bg      = (const float*)d_in[9];

    float* out = (float*)d_out;
    float* wsf = (float*)d_ws;
    float* payload        = wsf;            // 1024*12 floats
    float* sorted_payload = wsf + 12288;    // 1024*12 floats
    int*   count          = (int*)(wsf + 24576);

    prep_sort_kernel<<<1, N_G, 0, stream>>>(means3D, opac, shs, scales, rot,
                                            vm, pm, campos,
                                            out + 3*H_IMG*W_IMG,
                                            payload, sorted_payload, count);
    raster_kernel<<<(H_IMG*W_IMG)/64, 64, 0, stream>>>(sorted_payload, count, bg, out);
}

// Round 2
// 93.988 us; speedup vs baseline: 4.4226x; 4.4226x over previous
//
#include <hip/hip_runtime.h>
#include <stdint.h>

#define N_G   1024
#define H_IMG 128
#define W_IMG 128
#define TILE  8
#define TILES_X (W_IMG / TILE)            // 16
#define N_TILES (TILES_X * (H_IMG/TILE))  // 256
#define FXc   128.0f
#define FYc   128.0f

// ws layout (floats): payload[1024*12] | cull float4[1024] | keys u64[1024]
#define WS_PAYLOAD 0
#define WS_CULL    (N_G*12)          // float offset
#define WS_KEYS    (N_G*12 + N_G*4)  // float offset (u64 array, 16B aligned)

// ---------------- Kernel 1: per-gaussian preprocess (grid-parallel) ----------------
__global__ __launch_bounds__(64) void prep_kernel(
    const float* __restrict__ means3D, const float* __restrict__ opac,
    const float* __restrict__ shs,     const float* __restrict__ scales,
    const float* __restrict__ rot,     const float* __restrict__ vm,
    const float* __restrict__ pm,      const float* __restrict__ campos,
    float* __restrict__ radii_out,     float* __restrict__ payload,
    float4* __restrict__ cull,         unsigned long long* __restrict__ keys)
{
    const int n = blockIdx.x * 64 + threadIdx.x;
    if (n >= N_G) return;

    float mx = means3D[n*3+0], my = means3D[n*3+1], mz = means3D[n*3+2];

    float pv0   = mx*vm[0] + my*vm[4] + mz*vm[8]  + vm[12];
    float pv1   = mx*vm[1] + my*vm[5] + mz*vm[9]  + vm[13];
    float depth = mx*vm[2] + my*vm[6] + mz*vm[10] + vm[14];
    bool dvalid = depth > 0.2f;

    float ph0 = mx*pm[0] + my*pm[4] + mz*pm[8]  + pm[12];
    float ph1 = mx*pm[1] + my*pm[5] + mz*pm[9]  + pm[13];
    float ph3 = mx*pm[3] + my*pm[7] + mz*pm[11] + pm[15];
    float invw = 1.0f / (ph3 + 1e-7f);
    float pp0 = ph0 * invw, pp1 = ph1 * invw;

    float q0 = rot[n*4+0], q1 = rot[n*4+1], q2 = rot[n*4+2], q3 = rot[n*4+3];
    float qn = sqrtf(q0*q0 + q1*q1 + q2*q2 + q3*q3);
    float qr = q0/qn, qx = q1/qn, qy = q2/qn, qz = q3/qn;
    float R00 = 1.f - 2.f*(qy*qy + qz*qz), R01 = 2.f*(qx*qy - qr*qz), R02 = 2.f*(qx*qz + qr*qy);
    float R10 = 2.f*(qx*qy + qr*qz), R11 = 1.f - 2.f*(qx*qx + qz*qz), R12 = 2.f*(qy*qz - qr*qx);
    float R20 = 2.f*(qx*qz - qr*qy), R21 = 2.f*(qy*qz + qr*qx), R22 = 1.f - 2.f*(qx*qx + qy*qy);

    float s0 = scales[n*3+0], s1 = scales[n*3+1], s2 = scales[n*3+2];
    float M00=R00*s0, M01=R01*s1, M02=R02*s2;
    float M10=R10*s0, M11=R11*s1, M12=R12*s2;
    float M20=R20*s0, M21=R21*s1, M22=R22*s2;

    float S00 = M00*M00 + M01*M01 + M02*M02;
    float S01 = M00*M10 + M01*M11 + M02*M12;
    float S02 = M00*M20 + M01*M21 + M02*M22;
    float S11 = M10*M10 + M11*M11 + M12*M12;
    float S12 = M10*M20 + M11*M21 + M12*M22;
    float S22 = M20*M20 + M21*M21 + M22*M22;

    float tz   = dvalid ? depth : 1.0f;
    float txtz = fminf(fmaxf(pv0 / tz, -0.65f), 0.65f) * tz;
    float tytz = fminf(fmaxf(pv1 / tz, -0.65f), 0.65f) * tz;
    float J00 = FXc / tz, J02 = -FXc * txtz / (tz*tz);
    float J11 = FYc / tz, J12 = -FYc * tytz / (tz*tz);

    float T20k0 = J00*vm[0] + J02*vm[2];
    float T20k1 = J00*vm[4] + J02*vm[6];
    float T20k2 = J00*vm[8] + J02*vm[10];
    float T21k0 = J11*vm[1] + J12*vm[2];
    float T21k1 = J11*vm[5] + J12*vm[6];
    float T21k2 = J11*vm[9] + J12*vm[10];

    float U00 = T20k0*S00 + T20k1*S01 + T20k2*S02;
    float U01 = T20k0*S01 + T20k1*S11 + T20k2*S12;
    float U02 = T20k0*S02 + T20k1*S12 + T20k2*S22;
    float U10 = T21k0*S00 + T21k1*S01 + T21k2*S02;
    float U11 = T21k0*S01 + T21k1*S11 + T21k2*S12;
    float U12 = T21k0*S02 + T21k1*S12 + T21k2*S22;
    float cov00 = U00*T20k0 + U01*T20k1 + U02*T20k2;
    float cov01 = U00*T21k0 + U01*T21k1 + U02*T21k2;
    float cov11 = U10*T21k0 + U11*T21k1 + U12*T21k2;

    float a = cov00 + 0.3f, b = cov01, c = cov11 + 0.3f;
    float det = a*c - b*b;
    bool valid = dvalid && (det > 0.0f);
    float inv_det = (det > 0.0f) ? (1.0f / det) : 1.0f;
    float conA = c * inv_det, conB = -b * inv_det, conC = a * inv_det;

    float mid  = 0.5f * (a + c);
    float lam1 = mid + sqrtf(fmaxf(0.1f, mid*mid - det));
    radii_out[n] = valid ? ceilf(3.0f * sqrtf(lam1)) : 0.0f;

    float gx = ((pp0 + 1.0f) * (float)W_IMG - 1.0f) * 0.5f;
    float gy = ((pp1 + 1.0f) * (float)H_IMG - 1.0f) * 0.5f;

    float dxm = mx - campos[0], dym = my - campos[1], dzm = mz - campos[2];
    float dn = sqrtf(dxm*dxm + dym*dym + dzm*dzm);
    float sx = dxm/dn, sy = dym/dn, sz = dzm/dn;
    float xx = sx*sx, yy = sy*sy, zz = sz*sz;
    float xy = sx*sy, yz = sy*sz, xz = sx*sz;
    const float* sh = shs + n*48;
    float col[3];
    #pragma unroll
    for (int ch = 0; ch < 3; ++ch) {
        float res = 0.28209479177387814f * sh[0*3+ch]
            - 0.4886025119029199f * sy * sh[1*3+ch]
            + 0.4886025119029199f * sz * sh[2*3+ch]
            - 0.4886025119029199f * sx * sh[3*3+ch]
            + 1.0925484305920792f  * xy * sh[4*3+ch]
            + (-1.0925484305920792f) * yz * sh[5*3+ch]
            + 0.31539156525252005f * (2.f*zz - xx - yy) * sh[6*3+ch]
            + (-1.0925484305920792f) * xz * sh[7*3+ch]
            + 0.5462742152960396f  * (xx - yy) * sh[8*3+ch]
            + (-0.5900435899266435f) * sy * (3.f*xx - yy) * sh[9*3+ch]
            + 2.890611442640554f   * xy * sz * sh[10*3+ch]
            + (-0.4570457994644658f) * sy * (4.f*zz - xx - yy) * sh[11*3+ch]
            + 0.3731763325901154f  * sz * (2.f*zz - 3.f*xx - 3.f*yy) * sh[12*3+ch]
            + (-0.4570457994644658f) * sx * (4.f*zz - xx - yy) * sh[13*3+ch]
            + 1.445305721320277f   * sz * (xx - yy) * sh[14*3+ch]
            + (-0.5900435899266435f) * sx * (xx - 3.f*yy) * sh[15*3+ch];
        col[ch] = fmaxf(res + 0.5f, 0.0f);
    }

    float op = opac[n];
    float* pl = payload + n*12;
    pl[0]=gx; pl[1]=gy; pl[2]=conA; pl[3]=conB; pl[4]=conC; pl[5]=op;
    pl[6]=col[0]; pl[7]=col[1]; pl[8]=col[2]; pl[9]=0.f; pl[10]=0.f; pl[11]=0.f;

    // conservative cull radius^2: alpha >= 1/255 requires |d|^2 <= 2 ln(255 op) lam1
    float op255 = op * 255.0f;
    float rc2 = (valid && op255 > 1.0f) ? (2.0f * logf(op255) * lam1 * 1.01f + 1.0f)
                                        : -1.0f;
    cull[n] = make_float4(gx, gy, rc2, 0.0f);

    unsigned int kb = __float_as_uint(depth);   // depth>0.2 positive => bit order = value order
    keys[n] = ((unsigned long long)kb << 32) | (unsigned int)n;
}

// ---------------- Kernel 2: per-tile cull + sort + blend (1 wave / 8x8 tile) ----------------
__global__ __launch_bounds__(64) void raster_tile(
    const float* __restrict__ payload,
    const float4* __restrict__ cull,
    const unsigned long long* __restrict__ keys,
    const float* __restrict__ bg,
    float* __restrict__ out)
{
    __shared__ unsigned long long list[N_G];
    __shared__ float batch[64 * 12];
    __shared__ int cnt;

    const int lane = threadIdx.x;
    const int tile = blockIdx.x;
    const int tx = tile & (TILES_X - 1), ty = tile / TILES_X;
    const float x0 = (float)(tx * TILE), x1 = x0 + (float)(TILE - 1);
    const float y0 = (float)(ty * TILE), y1 = y0 + (float)(TILE - 1);

    if (lane == 0) cnt = 0;
    __syncthreads();

    // cull: circle-vs-tile-rect (pixel centers)
    for (int i = lane; i < N_G; i += 64) {
        float4 ci = cull[i];
        float cx = fminf(fmaxf(ci.x, x0), x1) - ci.x;
        float cy = fminf(fmaxf(ci.y, y0), y1) - ci.y;
        if (cx*cx + cy*cy <= ci.z) {
            int slot = atomicAdd(&cnt, 1);
            list[slot] = keys[i];
        }
    }
    __syncthreads();
    const int M = cnt;

    // pad to pow2 and bitonic sort by (depth_bits, idx) -> exact stable depth order
    int P = 1; while (P < M) P <<= 1;
    for (int i = M + lane; i < P; i += 64) list[i] = ~0ull;
    __syncthreads();
    for (int k = 2; k <= P; k <<= 1) {
        for (int j = k >> 1; j > 0; j >>= 1) {
            for (int i = lane; i < P; i += 64) {
                int l = i ^ j;
                if (l > i) {
                    unsigned long long ka = list[i], kb = list[l];
                    bool asc = ((i & k) == 0);
                    if ((ka > kb) == asc) { list[i] = kb; list[l] = ka; }
                }
            }
            __syncthreads();
        }
    }

    // blend front-to-back
    const float px = x0 + (float)(lane & (TILE - 1));
    const float py = y0 + (float)(lane / TILE);
    float T = 1.0f, Tfin = 1.0f, cr = 0.f, cg = 0.f, cb = 0.f;
    bool live = true;

    for (int base = 0; base < M; base += 64) {
        if (__ballot(live) == 0ull) break;
        int nb = min(64, M - base);
        if (lane < nb) {
            int idx = (int)(list[base + lane] & 0xFFFFFFFFu);
            const float4* pp = (const float4*)(payload + idx * 12);
            float4 p0 = pp[0], p1 = pp[1], p2 = pp[2];
            float4* bp = (float4*)(batch + lane * 12);
            bp[0] = p0; bp[1] = p1; bp[2] = p2;
        }
        __syncthreads();
        for (int j = 0; j < nb; ++j) {
            float4 g0 = *(const float4*)(batch + j * 12);      // gx gy A B
            float4 g1 = *(const float4*)(batch + j * 12 + 4);  // C op r g
            float  b2 = batch[j * 12 + 8];                     // b
            float dx = g0.x - px, dy = g0.y - py;
            float power = -0.5f * (g0.z*dx*dx + g1.x*dy*dy) - g0.w*dx*dy;
            float alpha = fminf(0.99f, g1.y * expf(power));
            if (live && power <= 0.0f && alpha >= (1.0f/255.0f)) {
                float Tnew = T * (1.0f - alpha);
                if (Tnew < 1e-4f) {
                    live = false;
                } else {
                    float w = T * alpha;
                    cr += w * g1.z; cg += w * g1.w; cb += w * b2;
                    Tfin *= (1.0f - alpha);
                    T = Tnew;
                }
            }
        }
        __syncthreads();
    }

    int p = (int)py * W_IMG + (int)px;
    out[p]                 = cr + bg[0] * Tfin;
    out[H_IMG*W_IMG + p]   = cg + bg[1] * Tfin;
    out[2*H_IMG*W_IMG + p] = cb + bg[2] * Tfin;
}

extern "C" void kernel_launch(void* const* d_in, const int* in_sizes, int n_in,
                              void* d_out, int out_size, void* d_ws, size_t ws_size,
                              hipStream_t stream) {
    const float* means3D = (const float*)d_in[0];
    const float* opac    = (const float*)d_in[2];
    const float* shs     = (const float*)d_in[3];
    const float* scales  = (const float*)d_in[4];
    const float* rot     = (const float*)d_in[5];
    const float* vm      = (const float*)d_in[6];
    const float* pm      = (const float*)d_in[7];
    const float* campos  = (const float*)d_in[8];
    const float* bg      = (const float*)d_in[9];

    float* out = (float*)d_out;
    float* wsf = (float*)d_ws;
    float*              payload = wsf + WS_PAYLOAD;
    float4*             cullv   = (float4*)(wsf + WS_CULL);
    unsigned long long* keys    = (unsigned long long*)(wsf + WS_KEYS);

    prep_kernel<<<N_G/64, 64, 0, stream>>>(means3D, opac, shs, scales, rot,
                                           vm, pm, campos,
                                           out + 3*H_IMG*W_IMG,
                                           payload, cullv, keys);
    raster_tile<<<N_TILES, 64, 0, stream>>>(payload, cullv, keys, bg, out);
}